// Round 1
// baseline (718.657 us; speedup 1.0000x reference)
//
#include <hip/hip_runtime.h>
#include <math.h>

// Problem constants
#define HH 180
#define WDIM 360
#define CDIM 512
#define NP 64800           // 180*360 positions
#define PL 184320          // 360*512 per-h plane (also idht norm)

typedef unsigned short u16;
typedef __attribute__((ext_vector_type(8))) short short8;  // 8 bf16 = 4 VGPR
typedef __attribute__((ext_vector_type(4))) float f4;      // 4 fp32 acc

__device__ __forceinline__ u16 f2bf(float f){
    unsigned u = __float_as_uint(f);
    return (u16)((u + 0x7fffu + ((u >> 16) & 1u)) >> 16);   // RNE
}
__device__ __forceinline__ void gl_lds16(const void* g, void* l){
    __builtin_amdgcn_global_load_lds((const __attribute__((address_space(1))) void*)g,
                                     (__attribute__((address_space(3))) void*)l, 16, 0, 0);
}

// ---------------- prep: cas matrices (bf16) + folded transposed weights ----------------
// casC [512][512] (symmetric); casW [360][384] (cols >=360 ZERO -> kills k-overread)
// wts = [w1a_t, w1b_t, w2a_t, w2b_t], each [8][64 o][64 i], 0.5 folded in.
__global__ void prep(const float* __restrict__ w1, const float* __restrict__ w2,
                     u16* __restrict__ casC, u16* __restrict__ casW, u16* __restrict__ wts)
{
    int idx = blockIdx.x * 256 + threadIdx.x;
    if (idx < 512*512){
        int i = idx >> 9, j = idx & 511;
        int m = (i * j) & 511;                       // exact angle reduction
        float a = (float)m * (6.283185307179586f / 512.0f);
        float s, c; __sincosf(a, &s, &c);
        casC[idx] = f2bf(c + s);
    }
    if (idx < 360*384){
        int i = idx / 384, j = idx - (idx / 384) * 384;
        u16 v = 0;
        if (j < 360){
            int m = (i * j) % 360;
            float a = (float)m * (6.283185307179586f / 360.0f);
            float s, c; __sincosf(a, &s, &c);
            v = f2bf(c + s);
        }
        casW[idx] = v;
    }
    if (idx < 131072){
        int s = idx >> 15, r = idx & 32767;
        int kb = r >> 12, o = (r >> 6) & 63, ii = r & 63;
        const float* w = (s < 2) ? w1 : w2;
        float v0 = w[kb*4096 + ii*64 + o];
        float v1 = w[32768 + kb*4096 + ii*64 + o];
        float v = 0.5f * ((s & 1) ? (v0 - v1) : (v0 + v1));
        wts[idx] = f2bf(v);
    }
}

// ---------------- MFMA GEMM: C(Mx512) = A(MxK) * B^T(512xK) ----------------
// 128x128 tile, 4 waves. LDS layout is k-chunk-major [4 chunks][128 rows][8 u16]
// -> every sequential 8-lane ds_read_b128 phase hits all 32 banks (conflict-free),
// and still stages as 8 contiguous 1KB global_load_lds segments per operand.
// ASTAGE=0: A bf16 [m][k] via global_load_lds. ASTAGE=1: A fp32 [m][k], staged
//   via float4 loads + bf16 pack + ds_write_b128.
// B always bf16 [n][k] rows via global_load_lds (over-read past k=K is harmless:
//   A-side zeros or buffer pad).
// STORE=0: bf16 [m][512]. STORE=1: bf16 transposed T[h][d][w] (m=(h,w), n=d).
// STORE=2: fp32 [m][512] = acc*scale + X (residual).
template<int ASTAGE, int STORE, int SWAP>
__global__ __launch_bounds__(256)
void gemm_k(const void* __restrict__ A, int ldA, long long sA, int clampA,
            const u16* __restrict__ B, int ldB, long long sB,
            void* __restrict__ C, long long sC, int Mreal,
            const float* __restrict__ X, float scale, int nK)
{
    __shared__ u16 As[4096];   // [4][128][8]
    __shared__ u16 Bs[4096];

    const int tid = threadIdx.x, wv = tid >> 6, l = tid & 63;
    const int l16 = l & 15, quad = l >> 4;
    const int z = blockIdx.z;
    const int bx = SWAP ? blockIdx.y : blockIdx.x;
    const int by = SWAP ? blockIdx.x : blockIdx.y;
    const int row0 = bx * 128, col0 = by * 128;

    // wave w stages row-half rh = w&1, chunks {w>>1, w>>1+2} of each operand
    const int rh = wv & 1, c0 = wv >> 1;

    const u16* gB = B + sB * z + (long long)(col0 + rh*64 + l) * ldB;
    u16* lB0 = Bs + c0*1024 + rh*512;
    u16* lB1 = lB0 + 2048;

    const u16* gA = nullptr; u16* lA0 = nullptr; u16* lA1 = nullptr;
    const float* gAf = nullptr; int arow = 0;
    if constexpr (ASTAGE == 0){
        int r = row0 + rh*64 + l; r = r <= clampA ? r : clampA;
        gA  = (const u16*)A + sA * z + (long long)r * ldA;
        lA0 = As + c0*1024 + rh*512;
        lA1 = lA0 + 2048;
    } else {
        int r = row0 + (tid >> 1); r = r <= clampA ? r : clampA;
        gAf  = (const float*)A + (long long)r * ldA + (tid & 1) * 16;
        arow = tid >> 1;
    }

    f4 acc[4][4];
    #pragma unroll
    for (int mt = 0; mt < 4; ++mt)
        #pragma unroll
        for (int nt = 0; nt < 4; ++nt)
            acc[mt][nt] = (f4)0.0f;

    const int mrow = (wv >> 1) * 64, ncol = (wv & 1) * 64;

    for (int kt = 0; kt < nK; ++kt){
        const int k0 = kt * 32;
        gl_lds16(gB + k0 + c0*8,     lB0);
        gl_lds16(gB + k0 + (c0+2)*8, lB1);
        if constexpr (ASTAGE == 0){
            gl_lds16(gA + k0 + c0*8,     lA0);
            gl_lds16(gA + k0 + (c0+2)*8, lA1);
        } else {
            const float* p = gAf + k0;
            float4 f0 = *(const float4*)(p);
            float4 f1 = *(const float4*)(p + 4);
            float4 f2 = *(const float4*)(p + 8);
            float4 f3 = *(const float4*)(p + 12);
            uint4 w0, w1;
            w0.x = (unsigned)f2bf(f0.x) | ((unsigned)f2bf(f0.y) << 16);
            w0.y = (unsigned)f2bf(f0.z) | ((unsigned)f2bf(f0.w) << 16);
            w0.z = (unsigned)f2bf(f1.x) | ((unsigned)f2bf(f1.y) << 16);
            w0.w = (unsigned)f2bf(f1.z) | ((unsigned)f2bf(f1.w) << 16);
            w1.x = (unsigned)f2bf(f2.x) | ((unsigned)f2bf(f2.y) << 16);
            w1.y = (unsigned)f2bf(f2.z) | ((unsigned)f2bf(f2.w) << 16);
            w1.z = (unsigned)f2bf(f3.x) | ((unsigned)f2bf(f3.y) << 16);
            w1.w = (unsigned)f2bf(f3.z) | ((unsigned)f2bf(f3.w) << 16);
            const int cb = (tid & 1) * 2;
            *(uint4*)&As[cb*1024       + arow*8] = w0;
            *(uint4*)&As[(cb+1)*1024   + arow*8] = w1;
        }
        __syncthreads();
        short8 af[4];
        #pragma unroll
        for (int mt = 0; mt < 4; ++mt)
            af[mt] = *(const short8*)&As[quad*1024 + (mrow + mt*16 + l16)*8];
        #pragma unroll
        for (int nt = 0; nt < 4; ++nt){
            short8 bfv = *(const short8*)&Bs[quad*1024 + (ncol + nt*16 + l16)*8];
            #pragma unroll
            for (int mt = 0; mt < 4; ++mt)
                acc[mt][nt] = __builtin_amdgcn_mfma_f32_16x16x32_bf16(af[mt], bfv, acc[mt][nt], 0, 0, 0);
        }
        __syncthreads();
    }

    // epilogue: C/D layout col=lane&15, row=quad*4+reg
    #pragma unroll
    for (int mt = 0; mt < 4; ++mt){
        #pragma unroll
        for (int i = 0; i < 4; ++i){
            int gr = row0 + mrow + mt*16 + quad*4 + i;
            if (gr >= Mreal) continue;
            int th = 0, tw = 0;
            if constexpr (STORE == 1){ th = gr / 360; tw = gr - th * 360; }
            #pragma unroll
            for (int nt = 0; nt < 4; ++nt){
                int gc = col0 + ncol + nt*16 + l16;
                if constexpr (STORE == 0){
                    ((u16*)C)[sC*z + (long long)gr*512 + gc] = f2bf(acc[mt][nt][i]);
                } else if constexpr (STORE == 1){
                    ((u16*)C)[((long long)th*512 + gc)*360 + tw] = f2bf(acc[mt][nt][i]);
                } else {
                    long long off = sC*z + (long long)gr*512 + gc;
                    ((float*)C)[off] = fmaf(acc[mt][nt][i], scale, X[off]);
                }
            }
        }
    }
}

// ---------------- MFMA block-MLP + softshrink ----------------
__global__ __launch_bounds__(256)
void mlp_k(const u16* __restrict__ xh, const u16* __restrict__ wts,
           const float* __restrict__ b1, const float* __restrict__ b2,
           u16* __restrict__ yout)
{
    __shared__ u16 sW0[64*72], sW1[64*72];
    __shared__ u16 sXh[64*72], sXn[64*72], s1k[64*72], s1n[64*72];
    __shared__ float sb[256];

    const int tid = threadIdx.x;
    const int wv = tid >> 6, l = tid & 63, lane16 = l & 15, quad = l >> 4;
    const int kb = blockIdx.y;
    const int p0 = blockIdx.x * 64;
    const int w16 = wv * 16;

    if (tid < 64){
        sb[tid]       = b1[kb*64 + tid];
        sb[64 + tid]  = b1[512 + kb*64 + tid];
        sb[128 + tid] = b2[kb*64 + tid];
        sb[192 + tid] = b2[512 + kb*64 + tid];
    }
    {
        const int r = tid >> 2, sg = (tid & 3) * 16;
        const u16* s0 = wts + kb*4096 + r*64 + sg;            // w1a_t
        const u16* s1 = wts + 32768 + kb*4096 + r*64 + sg;    // w1b_t
        *(uint4*)&sW0[r*72 + sg]     = *(const uint4*)s0;
        *(uint4*)&sW0[r*72 + sg + 8] = *(const uint4*)(s0 + 8);
        *(uint4*)&sW1[r*72 + sg]     = *(const uint4*)s1;
        *(uint4*)&sW1[r*72 + sg + 8] = *(const uint4*)(s1 + 8);

        int p = p0 + r; int pc = p <= 64799 ? p : 64799;
        int h = pc / 360; int v = pc - h * 360;
        int hn = (h == 0) ? 0 : (180 - h);
        int vn = (v == 0) ? 0 : (360 - v);
        long long bh = (long long)pc * 512 + kb*64 + sg;
        long long bn = (long long)(hn*360 + vn) * 512 + kb*64 + sg;
        *(uint4*)&sXh[r*72 + sg]     = *(const uint4*)&xh[bh];
        *(uint4*)&sXh[r*72 + sg + 8] = *(const uint4*)&xh[bh + 8];
        *(uint4*)&sXn[r*72 + sg]     = *(const uint4*)&xh[bn];
        *(uint4*)&sXn[r*72 + sg + 8] = *(const uint4*)&xh[bn + 8];
    }
    __syncthreads();

    // -------- layer 1 --------
    f4 aK[4], aN[4];
    #pragma unroll
    for (int nt = 0; nt < 4; ++nt){ aK[nt] = (f4)0.0f; aN[nt] = (f4)0.0f; }
    #pragma unroll
    for (int kq = 0; kq < 2; ++kq){
        short8 fxh = *(const short8*)&sXh[(w16 + lane16)*72 + kq*32 + quad*8];
        short8 fxn = *(const short8*)&sXn[(w16 + lane16)*72 + kq*32 + quad*8];
        #pragma unroll
        for (int nt = 0; nt < 4; ++nt){
            short8 wa = *(const short8*)&sW0[(nt*16 + lane16)*72 + kq*32 + quad*8];
            short8 wb = *(const short8*)&sW1[(nt*16 + lane16)*72 + kq*32 + quad*8];
            aK[nt] = __builtin_amdgcn_mfma_f32_16x16x32_bf16(fxh, wa, aK[nt], 0,0,0);
            aK[nt] = __builtin_amdgcn_mfma_f32_16x16x32_bf16(fxn, wb, aK[nt], 0,0,0);
            aN[nt] = __builtin_amdgcn_mfma_f32_16x16x32_bf16(fxn, wa, aN[nt], 0,0,0);
            aN[nt] = __builtin_amdgcn_mfma_f32_16x16x32_bf16(fxh, wb, aN[nt], 0,0,0);
        }
    }
    #pragma unroll
    for (int nt = 0; nt < 4; ++nt){
        int cc = nt*16 + lane16;
        #pragma unroll
        for (int i = 0; i < 4; ++i){
            int rr = w16 + quad*4 + i;
            float vk = fmaxf(aK[nt][i] + sb[cc], 0.f);
            float vn = fmaxf(aN[nt][i] + sb[64 + cc], 0.f);
            s1k[rr*72 + cc] = f2bf(vk);
            s1n[rr*72 + cc] = f2bf(vn);
        }
    }
    __syncthreads();

    // -------- swap weights to layer 2 --------
    {
        const int r = tid >> 2, sg = (tid & 3) * 16;
        const u16* s0 = wts + 65536 + kb*4096 + r*64 + sg;    // w2a_t
        const u16* s1 = wts + 98304 + kb*4096 + r*64 + sg;    // w2b_t
        *(uint4*)&sW0[r*72 + sg]     = *(const uint4*)s0;
        *(uint4*)&sW0[r*72 + sg + 8] = *(const uint4*)(s0 + 8);
        *(uint4*)&sW1[r*72 + sg]     = *(const uint4*)s1;
        *(uint4*)&sW1[r*72 + sg + 8] = *(const uint4*)(s1 + 8);
    }
    __syncthreads();

    // -------- layer 2a: o2k --------
    f4 k2[4];
    #pragma unroll
    for (int nt = 0; nt < 4; ++nt) k2[nt] = (f4)0.0f;
    #pragma unroll
    for (int kq = 0; kq < 2; ++kq){
        short8 a1k = *(const short8*)&s1k[(w16 + lane16)*72 + kq*32 + quad*8];
        short8 a1n = *(const short8*)&s1n[(w16 + lane16)*72 + kq*32 + quad*8];
        #pragma unroll
        for (int nt = 0; nt < 4; ++nt){
            short8 wa = *(const short8*)&sW0[(nt*16 + lane16)*72 + kq*32 + quad*8];
            short8 wb = *(const short8*)&sW1[(nt*16 + lane16)*72 + kq*32 + quad*8];
            k2[nt] = __builtin_amdgcn_mfma_f32_16x16x32_bf16(a1k, wa, k2[nt], 0,0,0);
            k2[nt] = __builtin_amdgcn_mfma_f32_16x16x32_bf16(a1n, wb, k2[nt], 0,0,0);
        }
    }
    #pragma unroll
    for (int nt = 0; nt < 4; ++nt){
        int cc = nt*16 + lane16;
        #pragma unroll
        for (int i = 0; i < 4; ++i){
            int rr = w16 + quad*4 + i;
            float v2 = k2[nt][i] + sb[128 + cc];
            k2[nt][i] = v2;                        // keep o2k (with bias) in regs
            sXh[rr*72 + cc] = f2bf(v2);            // reuse sXh as o2k A-operand
        }
    }
    __syncthreads();

    // -------- layer 2b: o2n (consumes o2k per source bug) + softshrink --------
    f4 n2[4];
    #pragma unroll
    for (int nt = 0; nt < 4; ++nt) n2[nt] = (f4)0.0f;
    #pragma unroll
    for (int kq = 0; kq < 2; ++kq){
        short8 a1n = *(const short8*)&s1n[(w16 + lane16)*72 + kq*32 + quad*8];
        short8 a2k = *(const short8*)&sXh[(w16 + lane16)*72 + kq*32 + quad*8];
        #pragma unroll
        for (int nt = 0; nt < 4; ++nt){
            short8 wa = *(const short8*)&sW0[(nt*16 + lane16)*72 + kq*32 + quad*8];
            short8 wb = *(const short8*)&sW1[(nt*16 + lane16)*72 + kq*32 + quad*8];
            n2[nt] = __builtin_amdgcn_mfma_f32_16x16x32_bf16(a1n, wa, n2[nt], 0,0,0);
            n2[nt] = __builtin_amdgcn_mfma_f32_16x16x32_bf16(a2k, wb, n2[nt], 0,0,0);
        }
    }
    #pragma unroll
    for (int nt = 0; nt < 4; ++nt){
        int cc = nt*16 + lane16;
        #pragma unroll
        for (int i = 0; i < 4; ++i){
            int rr = w16 + quad*4 + i;
            int p = p0 + rr;
            float y = k2[nt][i] + n2[nt][i] + sb[192 + cc];
            float ay = fabsf(y) - 0.01f;           // softshrink lambda
            float r0 = ay > 0.f ? (y > 0.f ? ay : -ay) : 0.f;
            if (p < 64800) yout[(long long)p * 512 + kb*64 + cc] = f2bf(r0);
        }
    }
}

// ---------------- launch ----------------
extern "C" void kernel_launch(void* const* d_in, const int* in_sizes, int n_in,
                              void* d_out, int out_size, void* d_ws, size_t ws_size,
                              hipStream_t stream) {
    const float* x  = (const float*)d_in[0];
    const float* w1 = (const float*)d_in[1];
    const float* b1 = (const float*)d_in[2];
    const float* w2 = (const float*)d_in[3];
    const float* b2 = (const float*)d_in[4];
    float* out = (float*)d_out;

    u16* ws   = (u16*)d_ws;
    u16* casC = ws;                        // 262144
    u16* casW = casC + 262144;             // 360*384 = 138240
    u16* wts  = casW + 138240;             // 131072
    u16* bufT = wts  + 131072;             // 33177600 + 64 pad (T1 / y)
    u16* bufP = bufT + 33177664;           // 33177600 + 64 pad (xh / Z)
    // total ws ~133.8 MB

    prep<<<1024, 256, 0, stream>>>(w1, w2, casC, casW, wts);

    dim3 gBig(4, 507, 1);     // col-block fastest -> sibling blocks share A via L3
    dim3 gW(3, 4, 180);
    dim3 gM(1013, 8, 1);

    // A) T1[h][d][w] = (x . casC) transposed          (channel contraction)
    gemm_k<1,1,1><<<gBig, 256, 0, stream>>>(x, 512, 0, 64799,
                                            casC, 512, 0,
                                            bufT, 0, 64800, nullptr, 0.f, 16);
    // B) xh[(h,v)][d] = sum_w casW[v][w] * T1[h][d][w]  (width contraction)
    gemm_k<0,0,0><<<gW, 256, 0, stream>>>(casW, 384, 0, 359,
                                          bufT, 360, (long long)PL,
                                          bufP, (long long)PL, 360, nullptr, 0.f, 12);
    // C) block-MLP + softshrink: xh -> y
    mlp_k<<<gM, 256, 0, stream>>>(bufP, wts, b1, b2, bufT);
    // D) Z[h][d][w] = (y . casC) transposed
    gemm_k<0,1,1><<<gBig, 256, 0, stream>>>(bufT, 512, 0, 64799,
                                            casC, 512, 0,
                                            bufP, 0, 64800, nullptr, 0.f, 16);
    // E) out[(h,v)][d] = (sum_w casW[v][w] * Z[h][d][w]) / 184320 + x
    gemm_k<0,2,0><<<gW, 256, 0, stream>>>(casW, 384, 0, 359,
                                          bufP, 360, (long long)PL,
                                          out, (long long)PL, 360,
                                          x, 1.0f/184320.0f, 12);
}

// Round 2
// 706.845 us; speedup vs baseline: 1.0167x; 1.0167x over previous
//
#include <hip/hip_runtime.h>
#include <math.h>

// Problem constants
#define HH 180
#define WDIM 360
#define CDIM 512
#define NP 64800           // 180*360 positions
#define PL 184320          // 360*512 per-h plane (also idht norm)

typedef unsigned short u16;
typedef __attribute__((ext_vector_type(8))) short short8;  // 8 bf16 = 4 VGPR
typedef __attribute__((ext_vector_type(4))) float f4;      // 4 fp32 acc

__device__ __forceinline__ u16 f2bf(float f){
    unsigned u = __float_as_uint(f);
    return (u16)((u + 0x7fffu + ((u >> 16) & 1u)) >> 16);   // RNE
}
__device__ __forceinline__ void gl_lds16(const void* g, void* l){
    __builtin_amdgcn_global_load_lds((const __attribute__((address_space(1))) void*)g,
                                     (__attribute__((address_space(3))) void*)l, 16, 0, 0);
}

// ---------------- prep: cas matrices (bf16) + folded transposed weights ----------------
__global__ void prep(const float* __restrict__ w1, const float* __restrict__ w2,
                     u16* __restrict__ casC, u16* __restrict__ casW, u16* __restrict__ wts)
{
    int idx = blockIdx.x * 256 + threadIdx.x;
    if (idx < 512*512){
        int i = idx >> 9, j = idx & 511;
        int m = (i * j) & 511;                       // exact angle reduction
        float a = (float)m * (6.283185307179586f / 512.0f);
        float s, c; __sincosf(a, &s, &c);
        casC[idx] = f2bf(c + s);
    }
    if (idx < 360*384){
        int i = idx / 384, j = idx - (idx / 384) * 384;
        u16 v = 0;
        if (j < 360){
            int m = (i * j) % 360;
            float a = (float)m * (6.283185307179586f / 360.0f);
            float s, c; __sincosf(a, &s, &c);
            v = f2bf(c + s);
        }
        casW[idx] = v;
    }
    if (idx < 131072){
        int s = idx >> 15, r = idx & 32767;
        int kb = r >> 12, o = (r >> 6) & 63, ii = r & 63;
        const float* w = (s < 2) ? w1 : w2;
        float v0 = w[kb*4096 + ii*64 + o];
        float v1 = w[32768 + kb*4096 + ii*64 + o];
        float v = 0.5f * ((s & 1) ? (v0 - v1) : (v0 + v1));
        wts[idx] = f2bf(v);
    }
}

// ---------------- MFMA GEMM: C(Mx512) = A(MxK) * B^T(512xK) ----------------
// 128x128 tile, 4 waves, DOUBLE-BUFFERED LDS (2-phase): stage tile t+1 is issued
// before compute of tile t; single vmcnt(0)+barrier per K-step.
// LDS layout per buffer is k-chunk-major [4 chunks][128 rows][8 u16].
// ASTAGE=0: A bf16 via global_load_lds. ASTAGE=1: A fp32, T14 split:
//   float4 loads issued BEFORE compute, pack+ds_write AFTER compute (write-late).
// SWAP=1: 1-D grid with m204 XCD-bijective swizzle, col-block fastest within each
//   XCD chunk -> the nbx col-siblings sharing a 128-row A panel land on ONE XCD L2.
// STORE=0: bf16 [m][512]. STORE=1: bf16 transposed T[h][d][w]. STORE=2: fp32 +residual.
template<int ASTAGE, int STORE, int SWAP>
__global__ __launch_bounds__(256)
void gemm_k(const void* __restrict__ A, int ldA, long long sA, int clampA,
            const u16* __restrict__ B, int ldB, long long sB,
            void* __restrict__ C, long long sC, int Mreal,
            const float* __restrict__ X, float scale, int nK, int nbx)
{
    __shared__ u16 As[2][4096];   // [buf][4 chunks][128 rows][8]
    __shared__ u16 Bs[2][4096];

    const int tid = threadIdx.x, wv = tid >> 6, l = tid & 63;
    const int l16 = l & 15, quad = l >> 4;
    const int z = blockIdx.z;

    int bx, by;
    if constexpr (SWAP){
        // m204 bijective XCD swizzle over a 1-D grid
        int n = gridDim.x;
        int q = n >> 3, r = n & 7;
        int xcd = blockIdx.x & 7, idx = blockIdx.x >> 3;
        int swz = (xcd < r ? xcd*(q+1) : r*(q+1) + (xcd-r)*q) + idx;
        bx = swz / nbx;            // row-block
        by = swz - bx * nbx;       // col-block (fastest within XCD chunk)
    } else {
        bx = blockIdx.x;
        by = blockIdx.y;
    }
    const int row0 = bx * 128, col0 = by * 128;

    // wave w stages row-half rh = w&1, chunks {w>>1, w>>1+2} of each operand
    const int rh = wv & 1, c0 = wv >> 1;

    const u16* gB = B + sB * z + (long long)(col0 + rh*64 + l) * ldB;

    const u16* gA = nullptr;
    const float* gAf = nullptr; int arow = 0, cb = 0;
    if constexpr (ASTAGE == 0){
        int r = row0 + rh*64 + l; r = r <= clampA ? r : clampA;
        gA = (const u16*)A + sA * z + (long long)r * ldA;
    } else {
        int r = row0 + (tid >> 1); r = r <= clampA ? r : clampA;
        gAf  = (const float*)A + (long long)r * ldA + (tid & 1) * 16;
        arow = tid >> 1;
        cb   = (tid & 1) * 2;
    }

    f4 acc[4][4];
    #pragma unroll
    for (int mt = 0; mt < 4; ++mt)
        #pragma unroll
        for (int nt = 0; nt < 4; ++nt)
            acc[mt][nt] = (f4)0.0f;

    const int mrow = (wv >> 1) * 64, ncol = (wv & 1) * 64;

    float4 f0, f1, f2, f3;                 // ASTAGE=1 in-flight regs (T14)

    auto stageB = [&](int buf, int k0){
        gl_lds16(gB + k0 + c0*8,     &Bs[buf][c0*1024     + rh*512]);
        gl_lds16(gB + k0 + (c0+2)*8, &Bs[buf][(c0+2)*1024 + rh*512]);
    };
    auto stageA = [&](int buf, int k0){
        gl_lds16(gA + k0 + c0*8,     &As[buf][c0*1024     + rh*512]);
        gl_lds16(gA + k0 + (c0+2)*8, &As[buf][(c0+2)*1024 + rh*512]);
    };
    auto issueA = [&](int k0){
        const float* p = gAf + k0;
        f0 = *(const float4*)(p);
        f1 = *(const float4*)(p + 4);
        f2 = *(const float4*)(p + 8);
        f3 = *(const float4*)(p + 12);
    };
    auto writeA = [&](int buf){
        uint4 w0, w1;
        w0.x = (unsigned)f2bf(f0.x) | ((unsigned)f2bf(f0.y) << 16);
        w0.y = (unsigned)f2bf(f0.z) | ((unsigned)f2bf(f0.w) << 16);
        w0.z = (unsigned)f2bf(f1.x) | ((unsigned)f2bf(f1.y) << 16);
        w0.w = (unsigned)f2bf(f1.z) | ((unsigned)f2bf(f1.w) << 16);
        w1.x = (unsigned)f2bf(f2.x) | ((unsigned)f2bf(f2.y) << 16);
        w1.y = (unsigned)f2bf(f2.z) | ((unsigned)f2bf(f2.w) << 16);
        w1.z = (unsigned)f2bf(f3.x) | ((unsigned)f2bf(f3.y) << 16);
        w1.w = (unsigned)f2bf(f3.z) | ((unsigned)f2bf(f3.w) << 16);
        *(uint4*)&As[buf][cb*1024     + arow*8] = w0;
        *(uint4*)&As[buf][(cb+1)*1024 + arow*8] = w1;
    };

    // ---- prologue: fill buffer 0 with tile 0 ----
    stageB(0, 0);
    if constexpr (ASTAGE == 0){
        stageA(0, 0);
    } else {
        issueA(0);
        writeA(0);
    }
    __syncthreads();

    int cur = 0;
    for (int kt = 0; kt < nK; ++kt){
        const bool more = (kt + 1 < nK);
        const int k0n = (kt + 1) * 32;
        if (more){
            stageB(cur ^ 1, k0n);
            if constexpr (ASTAGE == 0) stageA(cur ^ 1, k0n);
            else                       issueA(k0n);
        }
        // ---- compute tile kt from buf[cur] ----
        short8 af[4];
        #pragma unroll
        for (int mt = 0; mt < 4; ++mt)
            af[mt] = *(const short8*)&As[cur][quad*1024 + (mrow + mt*16 + l16)*8];
        #pragma unroll
        for (int nt = 0; nt < 4; ++nt){
            short8 bfv = *(const short8*)&Bs[cur][quad*1024 + (ncol + nt*16 + l16)*8];
            #pragma unroll
            for (int mt = 0; mt < 4; ++mt)
                acc[mt][nt] = __builtin_amdgcn_mfma_f32_16x16x32_bf16(af[mt], bfv, acc[mt][nt], 0, 0, 0);
        }
        if constexpr (ASTAGE == 1){
            if (more) writeA(cur ^ 1);   // write-late: own loads waited here, not before MFMA
        }
        __syncthreads();                  // drains vmcnt (next-tile gl_lds) + lgkmcnt
        cur ^= 1;
    }

    // epilogue: C/D layout col=lane&15, row=quad*4+reg
    #pragma unroll
    for (int mt = 0; mt < 4; ++mt){
        #pragma unroll
        for (int i = 0; i < 4; ++i){
            int gr = row0 + mrow + mt*16 + quad*4 + i;
            if (gr >= Mreal) continue;
            int th = 0, tw = 0;
            if constexpr (STORE == 1){ th = gr / 360; tw = gr - th * 360; }
            #pragma unroll
            for (int nt = 0; nt < 4; ++nt){
                int gc = col0 + ncol + nt*16 + l16;
                if constexpr (STORE == 0){
                    ((u16*)C)[sC*z + (long long)gr*512 + gc] = f2bf(acc[mt][nt][i]);
                } else if constexpr (STORE == 1){
                    ((u16*)C)[((long long)th*512 + gc)*360 + tw] = f2bf(acc[mt][nt][i]);
                } else {
                    long long off = sC*z + (long long)gr*512 + gc;
                    ((float*)C)[off] = fmaf(acc[mt][nt][i], scale, X[off]);
                }
            }
        }
    }
}

// ---------------- MFMA block-MLP + softshrink ----------------
__global__ __launch_bounds__(256)
void mlp_k(const u16* __restrict__ xh, const u16* __restrict__ wts,
           const float* __restrict__ b1, const float* __restrict__ b2,
           u16* __restrict__ yout)
{
    __shared__ u16 sW0[64*72], sW1[64*72];
    __shared__ u16 sXh[64*72], sXn[64*72], s1k[64*72], s1n[64*72];
    __shared__ float sb[256];

    const int tid = threadIdx.x;
    const int wv = tid >> 6, l = tid & 63, lane16 = l & 15, quad = l >> 4;
    const int kb = blockIdx.y;
    const int p0 = blockIdx.x * 64;
    const int w16 = wv * 16;

    if (tid < 64){
        sb[tid]       = b1[kb*64 + tid];
        sb[64 + tid]  = b1[512 + kb*64 + tid];
        sb[128 + tid] = b2[kb*64 + tid];
        sb[192 + tid] = b2[512 + kb*64 + tid];
    }
    {
        const int r = tid >> 2, sg = (tid & 3) * 16;
        const u16* s0 = wts + kb*4096 + r*64 + sg;            // w1a_t
        const u16* s1 = wts + 32768 + kb*4096 + r*64 + sg;    // w1b_t
        *(uint4*)&sW0[r*72 + sg]     = *(const uint4*)s0;
        *(uint4*)&sW0[r*72 + sg + 8] = *(const uint4*)(s0 + 8);
        *(uint4*)&sW1[r*72 + sg]     = *(const uint4*)s1;
        *(uint4*)&sW1[r*72 + sg + 8] = *(const uint4*)(s1 + 8);

        int p = p0 + r; int pc = p <= 64799 ? p : 64799;
        int h = pc / 360; int v = pc - h * 360;
        int hn = (h == 0) ? 0 : (180 - h);
        int vn = (v == 0) ? 0 : (360 - v);
        long long bh = (long long)pc * 512 + kb*64 + sg;
        long long bn = (long long)(hn*360 + vn) * 512 + kb*64 + sg;
        *(uint4*)&sXh[r*72 + sg]     = *(const uint4*)&xh[bh];
        *(uint4*)&sXh[r*72 + sg + 8] = *(const uint4*)&xh[bh + 8];
        *(uint4*)&sXn[r*72 + sg]     = *(const uint4*)&xh[bn];
        *(uint4*)&sXn[r*72 + sg + 8] = *(const uint4*)&xh[bn + 8];
    }
    __syncthreads();

    // -------- layer 1 --------
    f4 aK[4], aN[4];
    #pragma unroll
    for (int nt = 0; nt < 4; ++nt){ aK[nt] = (f4)0.0f; aN[nt] = (f4)0.0f; }
    #pragma unroll
    for (int kq = 0; kq < 2; ++kq){
        short8 fxh = *(const short8*)&sXh[(w16 + lane16)*72 + kq*32 + quad*8];
        short8 fxn = *(const short8*)&sXn[(w16 + lane16)*72 + kq*32 + quad*8];
        #pragma unroll
        for (int nt = 0; nt < 4; ++nt){
            short8 wa = *(const short8*)&sW0[(nt*16 + lane16)*72 + kq*32 + quad*8];
            short8 wb = *(const short8*)&sW1[(nt*16 + lane16)*72 + kq*32 + quad*8];
            aK[nt] = __builtin_amdgcn_mfma_f32_16x16x32_bf16(fxh, wa, aK[nt], 0,0,0);
            aK[nt] = __builtin_amdgcn_mfma_f32_16x16x32_bf16(fxn, wb, aK[nt], 0,0,0);
            aN[nt] = __builtin_amdgcn_mfma_f32_16x16x32_bf16(fxn, wa, aN[nt], 0,0,0);
            aN[nt] = __builtin_amdgcn_mfma_f32_16x16x32_bf16(fxh, wb, aN[nt], 0,0,0);
        }
    }
    #pragma unroll
    for (int nt = 0; nt < 4; ++nt){
        int cc = nt*16 + lane16;
        #pragma unroll
        for (int i = 0; i < 4; ++i){
            int rr = w16 + quad*4 + i;
            float vk = fmaxf(aK[nt][i] + sb[cc], 0.f);
            float vn = fmaxf(aN[nt][i] + sb[64 + cc], 0.f);
            s1k[rr*72 + cc] = f2bf(vk);
            s1n[rr*72 + cc] = f2bf(vn);
        }
    }
    __syncthreads();

    // -------- swap weights to layer 2 --------
    {
        const int r = tid >> 2, sg = (tid & 3) * 16;
        const u16* s0 = wts + 65536 + kb*4096 + r*64 + sg;    // w2a_t
        const u16* s1 = wts + 98304 + kb*4096 + r*64 + sg;    // w2b_t
        *(uint4*)&sW0[r*72 + sg]     = *(const uint4*)s0;
        *(uint4*)&sW0[r*72 + sg + 8] = *(const uint4*)(s0 + 8);
        *(uint4*)&sW1[r*72 + sg]     = *(const uint4*)s1;
        *(uint4*)&sW1[r*72 + sg + 8] = *(const uint4*)(s1 + 8);
    }
    __syncthreads();

    // -------- layer 2a: o2k --------
    f4 k2[4];
    #pragma unroll
    for (int nt = 0; nt < 4; ++nt) k2[nt] = (f4)0.0f;
    #pragma unroll
    for (int kq = 0; kq < 2; ++kq){
        short8 a1k = *(const short8*)&s1k[(w16 + lane16)*72 + kq*32 + quad*8];
        short8 a1n = *(const short8*)&s1n[(w16 + lane16)*72 + kq*32 + quad*8];
        #pragma unroll
        for (int nt = 0; nt < 4; ++nt){
            short8 wa = *(const short8*)&sW0[(nt*16 + lane16)*72 + kq*32 + quad*8];
            short8 wb = *(const short8*)&sW1[(nt*16 + lane16)*72 + kq*32 + quad*8];
            k2[nt] = __builtin_amdgcn_mfma_f32_16x16x32_bf16(a1k, wa, k2[nt], 0,0,0);
            k2[nt] = __builtin_amdgcn_mfma_f32_16x16x32_bf16(a1n, wb, k2[nt], 0,0,0);
        }
    }
    #pragma unroll
    for (int nt = 0; nt < 4; ++nt){
        int cc = nt*16 + lane16;
        #pragma unroll
        for (int i = 0; i < 4; ++i){
            int rr = w16 + quad*4 + i;
            float v2 = k2[nt][i] + sb[128 + cc];
            k2[nt][i] = v2;                        // keep o2k (with bias) in regs
            sXh[rr*72 + cc] = f2bf(v2);            // reuse sXh as o2k A-operand
        }
    }
    __syncthreads();

    // -------- layer 2b: o2n (consumes o2k per source bug) + softshrink --------
    f4 n2[4];
    #pragma unroll
    for (int nt = 0; nt < 4; ++nt) n2[nt] = (f4)0.0f;
    #pragma unroll
    for (int kq = 0; kq < 2; ++kq){
        short8 a1n = *(const short8*)&s1n[(w16 + lane16)*72 + kq*32 + quad*8];
        short8 a2k = *(const short8*)&sXh[(w16 + lane16)*72 + kq*32 + quad*8];
        #pragma unroll
        for (int nt = 0; nt < 4; ++nt){
            short8 wa = *(const short8*)&sW0[(nt*16 + lane16)*72 + kq*32 + quad*8];
            short8 wb = *(const short8*)&sW1[(nt*16 + lane16)*72 + kq*32 + quad*8];
            n2[nt] = __builtin_amdgcn_mfma_f32_16x16x32_bf16(a1n, wa, n2[nt], 0,0,0);
            n2[nt] = __builtin_amdgcn_mfma_f32_16x16x32_bf16(a2k, wb, n2[nt], 0,0,0);
        }
    }
    #pragma unroll
    for (int nt = 0; nt < 4; ++nt){
        int cc = nt*16 + lane16;
        #pragma unroll
        for (int i = 0; i < 4; ++i){
            int rr = w16 + quad*4 + i;
            int p = p0 + rr;
            float y = k2[nt][i] + n2[nt][i] + sb[192 + cc];
            float ay = fabsf(y) - 0.01f;           // softshrink lambda
            float r0 = ay > 0.f ? (y > 0.f ? ay : -ay) : 0.f;
            if (p < 64800) yout[(long long)p * 512 + kb*64 + cc] = f2bf(r0);
        }
    }
}

// ---------------- launch ----------------
extern "C" void kernel_launch(void* const* d_in, const int* in_sizes, int n_in,
                              void* d_out, int out_size, void* d_ws, size_t ws_size,
                              hipStream_t stream) {
    const float* x  = (const float*)d_in[0];
    const float* w1 = (const float*)d_in[1];
    const float* b1 = (const float*)d_in[2];
    const float* w2 = (const float*)d_in[3];
    const float* b2 = (const float*)d_in[4];
    float* out = (float*)d_out;

    u16* ws   = (u16*)d_ws;
    u16* casC = ws;                        // 262144
    u16* casW = casC + 262144;             // 360*384 = 138240
    u16* wts  = casW + 138240;             // 131072
    u16* bufT = wts  + 131072;             // 33177600 + 64 pad (T1 / y)
    u16* bufP = bufT + 33177664;           // 33177600 + 64 pad (xh / Z)
    // total ws ~133.8 MB

    prep<<<1024, 256, 0, stream>>>(w1, w2, casC, casW, wts);

    dim3 gBig(2028, 1, 1);    // 507 row-blocks x 4 col-blocks, XCD-swizzled in-kernel
    dim3 gW(3, 4, 180);
    dim3 gM(1013, 8, 1);

    // A) T1[h][d][w] = (x . casC) transposed          (channel contraction)
    gemm_k<1,1,1><<<gBig, 256, 0, stream>>>(x, 512, 0, 64799,
                                            casC, 512, 0,
                                            bufT, 0, 64800, nullptr, 0.f, 16, 4);
    // B) xh[(h,v)][d] = sum_w casW[v][w] * T1[h][d][w]  (width contraction)
    gemm_k<0,0,0><<<gW, 256, 0, stream>>>(casW, 384, 0, 359,
                                          bufT, 360, (long long)PL,
                                          bufP, (long long)PL, 360, nullptr, 0.f, 12, 1);
    // C) block-MLP + softshrink: xh -> y
    mlp_k<<<gM, 256, 0, stream>>>(bufP, wts, b1, b2, bufT);
    // D) Z[h][d][w] = (y . casC) transposed
    gemm_k<0,1,1><<<gBig, 256, 0, stream>>>(bufT, 512, 0, 64799,
                                            casC, 512, 0,
                                            bufP, 0, 64800, nullptr, 0.f, 16, 4);
    // E) out[(h,v)][d] = (sum_w casW[v][w] * Z[h][d][w]) / 184320 + x
    gemm_k<0,2,0><<<gW, 256, 0, stream>>>(casW, 384, 0, 359,
                                          bufP, 360, (long long)PL,
                                          out, (long long)PL, 360,
                                          x, 1.0f/184320.0f, 12, 1);
}